// Round 1
// baseline (4123.730 us; speedup 1.0000x reference)
//
#include <hip/hip_runtime.h>
#include <cstdint>
#include <cstddef>

#define BB 8
#define NN 4096
#define FF 64
#define SS 2048
#define KK 64
#define H1c 64
#define H2c 64
#define H3c 128
#define R2 0.04f
#define CAP 448

// Exact (numpy-order, non-fma) squared distance: (dx*dx + dy*dy) + dz*dz
__device__ __forceinline__ float d2_exact(float ax, float ay, float az,
                                          float bx, float by, float bz) {
  float dx = __fsub_rn(ax, bx);
  float dy = __fsub_rn(ay, by);
  float dz = __fsub_rn(az, bz);
  return __fadd_rn(__fadd_rn(__fmul_rn(dx, dx), __fmul_rn(dy, dy)), __fmul_rn(dz, dz));
}

// ---------------- Kernel 1: farthest point sampling (one block per cloud) ----
__global__ __launch_bounds__(1024) void fps_kernel(const float* __restrict__ pos,
                                                   float* __restrict__ pos_out,
                                                   float* __restrict__ batch_out) {
  __shared__ float plds[NN * 3];
  __shared__ float rv[16];
  __shared__ int ri[16];
  __shared__ int curs;
  const int b = blockIdx.x;
  const int tid = threadIdx.x;
  const float4* src = (const float4*)(pos + (size_t)b * NN * 3);
  float4* dstl = (float4*)plds;
#pragma unroll
  for (int k = 0; k < 3; k++) dstl[tid + k * 1024] = src[tid + k * 1024];
  __syncthreads();

  float px[4], py[4], pz[4], dmin[4];
#pragma unroll
  for (int i = 0; i < 4; i++) {
    int p = tid + i * 1024;
    px[i] = plds[p * 3 + 0];
    py[i] = plds[p * 3 + 1];
    pz[i] = plds[p * 3 + 2];
    dmin[i] = INFINITY;
  }
  int cur = 0;
  const int wid = tid >> 6, lane = tid & 63;

  for (int s = 0; s < SS; ++s) {
    float cx = plds[cur * 3 + 0], cy = plds[cur * 3 + 1], cz = plds[cur * 3 + 2];
    if (tid == 0) {
      int o = b * SS + s;
      pos_out[o * 3 + 0] = cx;
      pos_out[o * 3 + 1] = cy;
      pos_out[o * 3 + 2] = cz;
      batch_out[o] = (float)b;
    }
    float bv = -INFINITY;
    int bi = 0x7fffffff;
#pragma unroll
    for (int i = 0; i < 4; i++) {
      float d = d2_exact(px[i], py[i], pz[i], cx, cy, cz);
      dmin[i] = fminf(dmin[i], d);
      int idx = tid + i * 1024;
      if (dmin[i] > bv) { bv = dmin[i]; bi = idx; }
    }
#pragma unroll
    for (int off = 32; off; off >>= 1) {
      float ov = __shfl_xor(bv, off);
      int oi = __shfl_xor(bi, off);
      if (ov > bv || (ov == bv && oi < bi)) { bv = ov; bi = oi; }
    }
    if (lane == 0) { rv[wid] = bv; ri[wid] = bi; }
    __syncthreads();
    if (tid < 64) {
      float v = (lane < 16) ? rv[lane] : -INFINITY;
      int ii = (lane < 16) ? ri[lane] : 0x7fffffff;
#pragma unroll
      for (int off = 32; off; off >>= 1) {
        float ov = __shfl_xor(v, off);
        int oi = __shfl_xor(ii, off);
        if (ov > v || (ov == v && oi < ii)) { v = ov; ii = oi; }
      }
      if (tid == 0) curs = ii;
    }
    __syncthreads();
    cur = curs;
  }
}

// ---------------- Kernel 2: y1 = x @ W1[0:64,:] + b1 (no relu) ---------------
__global__ __launch_bounds__(256) void y1_kernel(const float* __restrict__ x,
                                                 const float* __restrict__ W1,
                                                 const float* __restrict__ b1,
                                                 float* __restrict__ y1) {
  __shared__ float xs[64][65];
  const int tid = threadIdx.x;
  const int r0 = blockIdx.x * 64;
  const float4* src = (const float4*)(x + (size_t)r0 * FF);
#pragma unroll
  for (int q = 0; q < 4; q++) {
    int p = tid + q * 256;
    float4 v = src[p];
    int row = (p * 4) >> 6, col = (p * 4) & 63;
    xs[row][col + 0] = v.x;
    xs[row][col + 1] = v.y;
    xs[row][col + 2] = v.z;
    xs[row][col + 3] = v.w;
  }
  __syncthreads();
  const int c4 = (tid & 15) * 4, kb = (tid >> 4) * 4;
  float acc[4][4];
#pragma unroll
  for (int kk = 0; kk < 4; kk++) {
    acc[kk][0] = b1[c4 + 0];
    acc[kk][1] = b1[c4 + 1];
    acc[kk][2] = b1[c4 + 2];
    acc[kk][3] = b1[c4 + 3];
  }
  for (int f = 0; f < FF; ++f) {
    float4 w = *(const float4*)(W1 + f * H1c + c4);
#pragma unroll
    for (int kk = 0; kk < 4; kk++) {
      float a = xs[kb + kk][f];
      acc[kk][0] += a * w.x;
      acc[kk][1] += a * w.y;
      acc[kk][2] += a * w.z;
      acc[kk][3] += a * w.w;
    }
  }
#pragma unroll
  for (int kk = 0; kk < 4; kk++) {
    float4 o;
    o.x = acc[kk][0]; o.y = acc[kk][1]; o.z = acc[kk][2]; o.w = acc[kk][3];
    *(float4*)(y1 + (size_t)(r0 + kb + kk) * H1c + c4) = o;
  }
}

// ---------------- Kernel 3: radius ball query, K nearest inside R -----------
__global__ __launch_bounds__(256) void ballq_kernel(const float* __restrict__ pos,
                                                    const float* __restrict__ pos_out,
                                                    int* __restrict__ nbr) {
  __shared__ float plds[NN * 3];
  __shared__ float d2c[4][CAP];
  __shared__ int idxc[4][CAP];
  const int tid = threadIdx.x;
  const int b = blockIdx.x >> 6;
  const int chunk = blockIdx.x & 63;
  const float4* src = (const float4*)(pos + (size_t)b * NN * 3);
  float4* dstl = (float4*)plds;
#pragma unroll
  for (int k = 0; k < 12; k++) dstl[tid + k * 256] = src[tid + k * 256];
  __syncthreads();

  const int w = tid >> 6, lane = tid & 63;
  for (int t8 = 0; t8 < 8; ++t8) {
    const int s = chunk * 32 + w * 8 + t8;
    const int g = b * SS + s;
    const float cx = pos_out[g * 3 + 0], cy = pos_out[g * 3 + 1], cz = pos_out[g * 3 + 2];
    int cnt = 0;
    for (int t = 0; t < 64; ++t) {
      int j = t * 64 + lane;
      float d2 = d2_exact(plds[j * 3 + 0], plds[j * 3 + 1], plds[j * 3 + 2], cx, cy, cz);
      bool pred = (d2 <= R2);
      unsigned long long mask = __ballot(pred);
      if (pred) {
        int p = cnt + __popcll(mask & ((1ull << lane) - 1ull));
        if (p < CAP) { d2c[w][p] = d2; idxc[w][p] = j; }
      }
      cnt += (int)__popcll(mask);
    }
    int M = cnt < CAP ? cnt : CAP;
    __syncthreads();  // make this wave's LDS list visible to itself safely

    if (M <= 64) {
      int v = (lane < M) ? (b * NN + idxc[w][lane]) : -1;
      nbr[(size_t)g * KK + lane] = v;
    } else {
      float ed[7];
      int ei[7];
#pragma unroll
      for (int q = 0; q < 7; q++) {
        int p = lane + q * 64;
        if (p < M) { ed[q] = d2c[w][p]; ei[q] = idxc[w][p]; }
        else { ed[q] = 0.f; ei[q] = -1; }
      }
      for (int it = 0; it < KK; ++it) {
        unsigned long long key = ~0ull;
#pragma unroll
        for (int q = 0; q < 7; q++) {
          if (ei[q] >= 0) {
            unsigned long long k2 =
                ((unsigned long long)__float_as_uint(ed[q]) << 32) | (unsigned)ei[q];
            if (k2 < key) key = k2;
          }
        }
#pragma unroll
        for (int off = 32; off; off >>= 1) {
          unsigned long long ok = __shfl_xor(key, off);
          if (ok < key) key = ok;
        }
        int widx = (int)(key & 0xffffffffull);
        if (lane == it) nbr[(size_t)g * KK + it] = b * NN + widx;
#pragma unroll
        for (int q = 0; q < 7; q++) {
          if (ei[q] == widx) ei[q] = -1;
        }
      }
    }
    __syncthreads();  // lists reused next iteration
  }
}

// ---------------- Kernel 4: per-centroid MLP (layers 1-3) + max aggregation -
__global__ __launch_bounds__(256) void mlp_kernel(const float* __restrict__ pos,
                                                  const float* __restrict__ y1,
                                                  const float* __restrict__ W1,
                                                  const float* __restrict__ W2,
                                                  const float* __restrict__ b2,
                                                  const float* __restrict__ W3,
                                                  const float* __restrict__ b3,
                                                  const int* __restrict__ nbr,
                                                  const float* __restrict__ pos_out,
                                                  float* __restrict__ x_out) {
  __shared__ float h1[64][65];
  __shared__ float h2[64][65];
  __shared__ int nl[64];
  const int g = blockIdx.x;
  const int tid = threadIdx.x;
  if (tid < 64) nl[tid] = nbr[(size_t)g * KK + tid];
  const float cx = pos_out[g * 3 + 0], cy = pos_out[g * 3 + 1], cz = pos_out[g * 3 + 2];
  __syncthreads();
  {
    const int k = tid >> 2, h0 = (tid & 3) * 16;
    const int j = nl[k];
    if (j >= 0) {
      const float* yr = y1 + (size_t)j * H1c;
      const float rx = pos[j * 3 + 0] - cx;
      const float ry = pos[j * 3 + 1] - cy;
      const float rz = pos[j * 3 + 2] - cz;
#pragma unroll
      for (int h = 0; h < 16; ++h) {
        int hh = h0 + h;
        float v = yr[hh] + rx * W1[64 * H1c + hh] + ry * W1[65 * H1c + hh] +
                  rz * W1[66 * H1c + hh];
        h1[k][hh] = fmaxf(v, 0.f);
      }
    } else {
#pragma unroll
      for (int h = 0; h < 16; ++h) h1[k][h0 + h] = 0.f;
    }
  }
  __syncthreads();
  {
    const int c4 = (tid & 15) * 4, kb = (tid >> 4) * 4;
    float acc[4][4];
#pragma unroll
    for (int kk = 0; kk < 4; kk++) {
      acc[kk][0] = b2[c4 + 0];
      acc[kk][1] = b2[c4 + 1];
      acc[kk][2] = b2[c4 + 2];
      acc[kk][3] = b2[c4 + 3];
    }
    for (int f = 0; f < H1c; ++f) {
      float4 wv = *(const float4*)(W2 + f * H2c + c4);
#pragma unroll
      for (int kk = 0; kk < 4; kk++) {
        float a = h1[kb + kk][f];
        acc[kk][0] += a * wv.x;
        acc[kk][1] += a * wv.y;
        acc[kk][2] += a * wv.z;
        acc[kk][3] += a * wv.w;
      }
    }
#pragma unroll
    for (int kk = 0; kk < 4; kk++) {
      h2[kb + kk][c4 + 0] = fmaxf(acc[kk][0], 0.f);
      h2[kb + kk][c4 + 1] = fmaxf(acc[kk][1], 0.f);
      h2[kb + kk][c4 + 2] = fmaxf(acc[kk][2], 0.f);
      h2[kb + kk][c4 + 3] = fmaxf(acc[kk][3], 0.f);
    }
  }
  __syncthreads();
  {
    const int c4 = (tid & 31) * 4, kb = (tid >> 5) * 8;
    float acc[8][4];
#pragma unroll
    for (int kk = 0; kk < 8; kk++) {
      acc[kk][0] = b3[c4 + 0];
      acc[kk][1] = b3[c4 + 1];
      acc[kk][2] = b3[c4 + 2];
      acc[kk][3] = b3[c4 + 3];
    }
    for (int f = 0; f < H2c; ++f) {
      float4 wv = *(const float4*)(W3 + f * H3c + c4);
#pragma unroll
      for (int kk = 0; kk < 8; kk++) {
        float a = h2[kb + kk][f];
        acc[kk][0] += a * wv.x;
        acc[kk][1] += a * wv.y;
        acc[kk][2] += a * wv.z;
        acc[kk][3] += a * wv.w;
      }
    }
    float pm[4] = {-INFINITY, -INFINITY, -INFINITY, -INFINITY};
#pragma unroll
    for (int kk = 0; kk < 8; kk++) {
      if (nl[kb + kk] >= 0) {
        pm[0] = fmaxf(pm[0], fmaxf(acc[kk][0], 0.f));
        pm[1] = fmaxf(pm[1], fmaxf(acc[kk][1], 0.f));
        pm[2] = fmaxf(pm[2], fmaxf(acc[kk][2], 0.f));
        pm[3] = fmaxf(pm[3], fmaxf(acc[kk][3], 0.f));
      }
    }
    float* red = &h1[0][0];  // reuse as [8][128]
    red[(tid >> 5) * H3c + c4 + 0] = pm[0];
    red[(tid >> 5) * H3c + c4 + 1] = pm[1];
    red[(tid >> 5) * H3c + c4 + 2] = pm[2];
    red[(tid >> 5) * H3c + c4 + 3] = pm[3];
    __syncthreads();
    if (tid < H3c) {
      float m = -INFINITY;
#pragma unroll
      for (int r = 0; r < 8; r++) m = fmaxf(m, red[r * H3c + tid]);
      x_out[(size_t)g * H3c + tid] = m;
    }
  }
}

extern "C" void kernel_launch(void* const* d_in, const int* in_sizes, int n_in,
                              void* d_out, int out_size, void* d_ws, size_t ws_size,
                              hipStream_t stream) {
  const float* x = (const float*)d_in[0];
  const float* pos = (const float*)d_in[1];
  // d_in[2] = batch (int32) unused: clouds are equal-size by construction
  const float* W1 = (const float*)d_in[3];
  const float* b1 = (const float*)d_in[4];
  const float* W2 = (const float*)d_in[5];
  const float* b2 = (const float*)d_in[6];
  const float* W3 = (const float*)d_in[7];
  const float* b3 = (const float*)d_in[8];

  float* out = (float*)d_out;
  float* x_out = out;                                    // [B*S, 128]
  float* pos_out = out + (size_t)BB * SS * H3c;          // [B*S, 3]
  float* batch_out = pos_out + (size_t)BB * SS * 3;      // [B*S]

  const size_t y1_bytes = (size_t)BB * NN * H1c * sizeof(float);   // 8 MB
  const size_t nbr_bytes = (size_t)BB * SS * KK * sizeof(int);     // 4 MB
  if (ws_size < y1_bytes + nbr_bytes) return;
  float* y1 = (float*)d_ws;
  int* nbr = (int*)((char*)d_ws + y1_bytes);

  fps_kernel<<<BB, 1024, 0, stream>>>(pos, pos_out, batch_out);
  y1_kernel<<<(BB * NN) / 64, 256, 0, stream>>>(x, W1, b1, y1);
  ballq_kernel<<<BB * 64, 256, 0, stream>>>(pos, pos_out, nbr);
  mlp_kernel<<<BB * SS, 256, 0, stream>>>(pos, y1, W1, W2, b2, W3, b3, nbr, pos_out, x_out);
}

// Round 2
// 2137.973 us; speedup vs baseline: 1.9288x; 1.9288x over previous
//
#include <hip/hip_runtime.h>
#include <cstdint>
#include <cstddef>

#define BB 8
#define NN 4096
#define FF 64
#define SS 2048
#define KK 64
#define H1c 64
#define H2c 64
#define H3c 128
#define R2 0.04f
#define CAP 448

typedef unsigned long long ull;

// Exact (numpy-order, non-fma) squared distance: (dx*dx + dy*dy) + dz*dz
__device__ __forceinline__ float d2_exact(float ax, float ay, float az,
                                          float bx, float by, float bz) {
  float dx = __fsub_rn(ax, bx);
  float dy = __fsub_rn(ay, by);
  float dz = __fsub_rn(az, bz);
  return __fadd_rn(__fadd_rn(__fmul_rn(dx, dx), __fmul_rn(dy, dy)), __fmul_rn(dz, dz));
}

// ---------------- Kernel 1: farthest point sampling (one block per cloud) ----
// 256 threads, 16 contiguous points per thread (lane order == index order).
// Per step: d2+dmin update (ILP), local argmax via packed u64 key, wave-level
// value max via DPP (identity 0 is safe: d2 >= 0), ballot+ctz+readlane for the
// winning key, single barrier with double-buffered per-wave key slots.
__global__ __launch_bounds__(256) void fps_kernel(const float* __restrict__ pos,
                                                  float* __restrict__ pos_out,
                                                  float* __restrict__ batch_out) {
  __shared__ float plds[NN * 3];
  __shared__ ull wkey[2][4];
  const int b = blockIdx.x;
  const int tid = threadIdx.x;
  const float4* src = (const float4*)(pos + (size_t)b * NN * 3);
  float4* dstl = (float4*)plds;
#pragma unroll
  for (int k = 0; k < 12; ++k) dstl[tid + k * 256] = src[tid + k * 256];
  __syncthreads();

  float px[16], py[16], pz[16], dmin[16];
#pragma unroll
  for (int i = 0; i < 16; ++i) {
    int p = tid * 16 + i;
    px[i] = plds[p * 3 + 0];
    py[i] = plds[p * 3 + 1];
    pz[i] = plds[p * 3 + 2];
    dmin[i] = INFINITY;
  }
  const int lane = tid & 63, wv = tid >> 6;
  float cx = plds[0], cy = plds[1], cz = plds[2];

  for (int s = 0; s < SS; ++s) {
    if (tid == 0) {
      int o = b * SS + s;
      pos_out[o * 3 + 0] = cx;
      pos_out[o * 3 + 1] = cy;
      pos_out[o * 3 + 2] = cz;
      batch_out[o] = (float)b;
    }
    // update dmin; build packed keys (value_bits<<32 | ~idx) -> max key ==
    // (max value, tie -> lowest idx) == numpy argmax first-occurrence.
    ull kk[16];
#pragma unroll
    for (int i = 0; i < 16; ++i) {
      float d = d2_exact(px[i], py[i], pz[i], cx, cy, cz);
      dmin[i] = fminf(dmin[i], d);
      kk[i] = ((ull)__float_as_uint(dmin[i]) << 32) | (unsigned)(~(tid * 16 + i));
    }
#pragma unroll
    for (int st = 1; st < 16; st <<= 1)
#pragma unroll
      for (int i = 0; i < 16; i += 2 * st)
        if (kk[i + st] > kk[i]) kk[i] = kk[i + st];
    const ull best = kk[0];

    // wave-level max of the 32-bit value via DPP (positive float bits ->
    // integer max is exact). Result lands in lane 63.
    int v = (int)(unsigned)(best >> 32);
    v = max(v, __builtin_amdgcn_update_dpp(0, v, 0x111, 0xf, 0xf, true));  // row_shr:1
    v = max(v, __builtin_amdgcn_update_dpp(0, v, 0x112, 0xf, 0xf, true));  // row_shr:2
    v = max(v, __builtin_amdgcn_update_dpp(0, v, 0x114, 0xf, 0xf, true));  // row_shr:4
    v = max(v, __builtin_amdgcn_update_dpp(0, v, 0x118, 0xf, 0xf, true));  // row_shr:8
    v = max(v, __builtin_amdgcn_update_dpp(0, v, 0x142, 0xf, 0xf, true));  // row_bcast:15
    v = max(v, __builtin_amdgcn_update_dpp(0, v, 0x143, 0xf, 0xf, true));  // row_bcast:31
    const int wmax = __builtin_amdgcn_readlane(v, 63);

    // lowest lane holding the max value owns the lowest point index (chunks
    // are ascending in lane order); fetch its packed key via readlane.
    const bool pred = ((int)(unsigned)(best >> 32) == wmax);
    const ull bal = __ballot(pred);
    const int wl = (int)__builtin_ctzll(bal);
    const unsigned klo =
        (unsigned)__builtin_amdgcn_readlane((int)(unsigned)(best & 0xffffffffu), wl);
    if (lane == 0) wkey[s & 1][wv] = ((ull)(unsigned)wmax << 32) | klo;
    __syncthreads();

    const ull k0 = wkey[s & 1][0], k1 = wkey[s & 1][1];
    const ull k2 = wkey[s & 1][2], k3 = wkey[s & 1][3];
    ull ka = k0 > k1 ? k0 : k1;
    const ull kb2 = k2 > k3 ? k2 : k3;
    if (kb2 > ka) ka = kb2;
    const int cur = (int)(~(unsigned)(ka & 0xffffffffu));
    cx = plds[cur * 3 + 0];
    cy = plds[cur * 3 + 1];
    cz = plds[cur * 3 + 2];
  }
}

// ---------------- Kernel 2: y1 = x @ W1[0:64,:] + b1 (no relu) ---------------
__global__ __launch_bounds__(256) void y1_kernel(const float* __restrict__ x,
                                                 const float* __restrict__ W1,
                                                 const float* __restrict__ b1,
                                                 float* __restrict__ y1) {
  __shared__ float xs[64][65];
  const int tid = threadIdx.x;
  const int r0 = blockIdx.x * 64;
  const float4* src = (const float4*)(x + (size_t)r0 * FF);
#pragma unroll
  for (int q = 0; q < 4; q++) {
    int p = tid + q * 256;
    float4 v = src[p];
    int row = (p * 4) >> 6, col = (p * 4) & 63;
    xs[row][col + 0] = v.x;
    xs[row][col + 1] = v.y;
    xs[row][col + 2] = v.z;
    xs[row][col + 3] = v.w;
  }
  __syncthreads();
  const int c4 = (tid & 15) * 4, kb = (tid >> 4) * 4;
  float acc[4][4];
#pragma unroll
  for (int kk = 0; kk < 4; kk++) {
    acc[kk][0] = b1[c4 + 0];
    acc[kk][1] = b1[c4 + 1];
    acc[kk][2] = b1[c4 + 2];
    acc[kk][3] = b1[c4 + 3];
  }
  for (int f = 0; f < FF; ++f) {
    float4 w = *(const float4*)(W1 + f * H1c + c4);
#pragma unroll
    for (int kk = 0; kk < 4; kk++) {
      float a = xs[kb + kk][f];
      acc[kk][0] += a * w.x;
      acc[kk][1] += a * w.y;
      acc[kk][2] += a * w.z;
      acc[kk][3] += a * w.w;
    }
  }
#pragma unroll
  for (int kk = 0; kk < 4; kk++) {
    float4 o;
    o.x = acc[kk][0]; o.y = acc[kk][1]; o.z = acc[kk][2]; o.w = acc[kk][3];
    *(float4*)(y1 + (size_t)(r0 + kb + kk) * H1c + c4) = o;
  }
}

// ---------------- Kernel 3: radius ball query, K nearest inside R -----------
__global__ __launch_bounds__(256) void ballq_kernel(const float* __restrict__ pos,
                                                    const float* __restrict__ pos_out,
                                                    int* __restrict__ nbr) {
  __shared__ float plds[NN * 3];
  __shared__ float d2c[4][CAP];
  __shared__ int idxc[4][CAP];
  const int tid = threadIdx.x;
  const int b = blockIdx.x >> 6;
  const int chunk = blockIdx.x & 63;
  const float4* src = (const float4*)(pos + (size_t)b * NN * 3);
  float4* dstl = (float4*)plds;
#pragma unroll
  for (int k = 0; k < 12; k++) dstl[tid + k * 256] = src[tid + k * 256];
  __syncthreads();

  const int w = tid >> 6, lane = tid & 63;
  for (int t8 = 0; t8 < 8; ++t8) {
    const int s = chunk * 32 + w * 8 + t8;
    const int g = b * SS + s;
    const float cx = pos_out[g * 3 + 0], cy = pos_out[g * 3 + 1], cz = pos_out[g * 3 + 2];
    int cnt = 0;
    for (int t = 0; t < 64; ++t) {
      int j = t * 64 + lane;
      float d2 = d2_exact(plds[j * 3 + 0], plds[j * 3 + 1], plds[j * 3 + 2], cx, cy, cz);
      bool pred = (d2 <= R2);
      unsigned long long mask = __ballot(pred);
      if (pred) {
        int p = cnt + __popcll(mask & ((1ull << lane) - 1ull));
        if (p < CAP) { d2c[w][p] = d2; idxc[w][p] = j; }
      }
      cnt += (int)__popcll(mask);
    }
    int M = cnt < CAP ? cnt : CAP;
    __syncthreads();  // make this wave's LDS list visible to itself safely

    if (M <= 64) {
      int v = (lane < M) ? (b * NN + idxc[w][lane]) : -1;
      nbr[(size_t)g * KK + lane] = v;
    } else {
      float ed[7];
      int ei[7];
#pragma unroll
      for (int q = 0; q < 7; q++) {
        int p = lane + q * 64;
        if (p < M) { ed[q] = d2c[w][p]; ei[q] = idxc[w][p]; }
        else { ed[q] = 0.f; ei[q] = -1; }
      }
      for (int it = 0; it < KK; ++it) {
        unsigned long long key = ~0ull;
#pragma unroll
        for (int q = 0; q < 7; q++) {
          if (ei[q] >= 0) {
            unsigned long long k2 =
                ((unsigned long long)__float_as_uint(ed[q]) << 32) | (unsigned)ei[q];
            if (k2 < key) key = k2;
          }
        }
#pragma unroll
        for (int off = 32; off; off >>= 1) {
          unsigned long long ok = __shfl_xor(key, off);
          if (ok < key) key = ok;
        }
        int widx = (int)(key & 0xffffffffull);
        if (lane == it) nbr[(size_t)g * KK + it] = b * NN + widx;
#pragma unroll
        for (int q = 0; q < 7; q++) {
          if (ei[q] == widx) ei[q] = -1;
        }
      }
    }
    __syncthreads();  // lists reused next iteration
  }
}

// ---------------- Kernel 4: per-centroid MLP (layers 1-3) + max aggregation -
__global__ __launch_bounds__(256) void mlp_kernel(const float* __restrict__ pos,
                                                  const float* __restrict__ y1,
                                                  const float* __restrict__ W1,
                                                  const float* __restrict__ W2,
                                                  const float* __restrict__ b2,
                                                  const float* __restrict__ W3,
                                                  const float* __restrict__ b3,
                                                  const int* __restrict__ nbr,
                                                  const float* __restrict__ pos_out,
                                                  float* __restrict__ x_out) {
  __shared__ float h1[64][65];
  __shared__ float h2[64][65];
  __shared__ int nl[64];
  const int g = blockIdx.x;
  const int tid = threadIdx.x;
  if (tid < 64) nl[tid] = nbr[(size_t)g * KK + tid];
  const float cx = pos_out[g * 3 + 0], cy = pos_out[g * 3 + 1], cz = pos_out[g * 3 + 2];
  __syncthreads();
  {
    const int k = tid >> 2, h0 = (tid & 3) * 16;
    const int j = nl[k];
    if (j >= 0) {
      const float* yr = y1 + (size_t)j * H1c;
      const float rx = pos[j * 3 + 0] - cx;
      const float ry = pos[j * 3 + 1] - cy;
      const float rz = pos[j * 3 + 2] - cz;
#pragma unroll
      for (int h = 0; h < 16; ++h) {
        int hh = h0 + h;
        float v = yr[hh] + rx * W1[64 * H1c + hh] + ry * W1[65 * H1c + hh] +
                  rz * W1[66 * H1c + hh];
        h1[k][hh] = fmaxf(v, 0.f);
      }
    } else {
#pragma unroll
      for (int h = 0; h < 16; ++h) h1[k][h0 + h] = 0.f;
    }
  }
  __syncthreads();
  {
    const int c4 = (tid & 15) * 4, kb = (tid >> 4) * 4;
    float acc[4][4];
#pragma unroll
    for (int kk = 0; kk < 4; kk++) {
      acc[kk][0] = b2[c4 + 0];
      acc[kk][1] = b2[c4 + 1];
      acc[kk][2] = b2[c4 + 2];
      acc[kk][3] = b2[c4 + 3];
    }
    for (int f = 0; f < H1c; ++f) {
      float4 wv = *(const float4*)(W2 + f * H2c + c4);
#pragma unroll
      for (int kk = 0; kk < 4; kk++) {
        float a = h1[kb + kk][f];
        acc[kk][0] += a * wv.x;
        acc[kk][1] += a * wv.y;
        acc[kk][2] += a * wv.z;
        acc[kk][3] += a * wv.w;
      }
    }
#pragma unroll
    for (int kk = 0; kk < 4; kk++) {
      h2[kb + kk][c4 + 0] = fmaxf(acc[kk][0], 0.f);
      h2[kb + kk][c4 + 1] = fmaxf(acc[kk][1], 0.f);
      h2[kb + kk][c4 + 2] = fmaxf(acc[kk][2], 0.f);
      h2[kb + kk][c4 + 3] = fmaxf(acc[kk][3], 0.f);
    }
  }
  __syncthreads();
  {
    const int c4 = (tid & 31) * 4, kb = (tid >> 5) * 8;
    float acc[8][4];
#pragma unroll
    for (int kk = 0; kk < 8; kk++) {
      acc[kk][0] = b3[c4 + 0];
      acc[kk][1] = b3[c4 + 1];
      acc[kk][2] = b3[c4 + 2];
      acc[kk][3] = b3[c4 + 3];
    }
    for (int f = 0; f < H2c; ++f) {
      float4 wv = *(const float4*)(W3 + f * H3c + c4);
#pragma unroll
      for (int kk = 0; kk < 8; kk++) {
        float a = h2[kb + kk][f];
        acc[kk][0] += a * wv.x;
        acc[kk][1] += a * wv.y;
        acc[kk][2] += a * wv.z;
        acc[kk][3] += a * wv.w;
      }
    }
    float pm[4] = {-INFINITY, -INFINITY, -INFINITY, -INFINITY};
#pragma unroll
    for (int kk = 0; kk < 8; kk++) {
      if (nl[kb + kk] >= 0) {
        pm[0] = fmaxf(pm[0], fmaxf(acc[kk][0], 0.f));
        pm[1] = fmaxf(pm[1], fmaxf(acc[kk][1], 0.f));
        pm[2] = fmaxf(pm[2], fmaxf(acc[kk][2], 0.f));
        pm[3] = fmaxf(pm[3], fmaxf(acc[kk][3], 0.f));
      }
    }
    float* red = &h1[0][0];  // reuse as [8][128]
    red[(tid >> 5) * H3c + c4 + 0] = pm[0];
    red[(tid >> 5) * H3c + c4 + 1] = pm[1];
    red[(tid >> 5) * H3c + c4 + 2] = pm[2];
    red[(tid >> 5) * H3c + c4 + 3] = pm[3];
    __syncthreads();
    if (tid < H3c) {
      float m = -INFINITY;
#pragma unroll
      for (int r = 0; r < 8; r++) m = fmaxf(m, red[r * H3c + tid]);
      x_out[(size_t)g * H3c + tid] = m;
    }
  }
}

extern "C" void kernel_launch(void* const* d_in, const int* in_sizes, int n_in,
                              void* d_out, int out_size, void* d_ws, size_t ws_size,
                              hipStream_t stream) {
  const float* x = (const float*)d_in[0];
  const float* pos = (const float*)d_in[1];
  // d_in[2] = batch (int32) unused: clouds are equal-size by construction
  const float* W1 = (const float*)d_in[3];
  const float* b1 = (const float*)d_in[4];
  const float* W2 = (const float*)d_in[5];
  const float* b2 = (const float*)d_in[6];
  const float* W3 = (const float*)d_in[7];
  const float* b3 = (const float*)d_in[8];

  float* out = (float*)d_out;
  float* x_out = out;                                    // [B*S, 128]
  float* pos_out = out + (size_t)BB * SS * H3c;          // [B*S, 3]
  float* batch_out = pos_out + (size_t)BB * SS * 3;      // [B*S]

  const size_t y1_bytes = (size_t)BB * NN * H1c * sizeof(float);   // 8 MB
  const size_t nbr_bytes = (size_t)BB * SS * KK * sizeof(int);     // 4 MB
  if (ws_size < y1_bytes + nbr_bytes) return;
  float* y1 = (float*)d_ws;
  int* nbr = (int*)((char*)d_ws + y1_bytes);

  fps_kernel<<<BB, 256, 0, stream>>>(pos, pos_out, batch_out);
  y1_kernel<<<(BB * NN) / 64, 256, 0, stream>>>(x, W1, b1, y1);
  ballq_kernel<<<BB * 64, 256, 0, stream>>>(pos, pos_out, nbr);
  mlp_kernel<<<BB * SS, 256, 0, stream>>>(pos, y1, W1, W2, b2, W3, b3, nbr, pos_out, x_out);
}